// Round 3
// baseline (622.972 us; speedup 1.0000x reference)
//
#include <hip/hip_runtime.h>
#include <hip/hip_bf16.h>

#define B_ 4
#define C_ 256
#define N_ 4096

typedef unsigned short u16;
typedef __attribute__((ext_vector_type(8))) short bf16x8;
typedef __attribute__((ext_vector_type(4))) float f32x4;

static __device__ __forceinline__ u16 f2bf(float f) {
    unsigned u = __float_as_uint(f);
    unsigned r = (u + 0x7FFFu + ((u >> 16) & 1u)) >> 16;
    return (u16)r;
}

static __device__ __forceinline__ f32x4 mfma16(bf16x8 a, bf16x8 b, f32x4 c) {
    return __builtin_amdgcn_mfma_f32_16x16x32_bf16(a, b, c, 0, 0, 0);
}

// ---------------- kernel 1: weights f32 -> bf16 ----------------
__global__ void wconv_kernel(const float* __restrict__ wq, const float* __restrict__ wk,
                             const float* __restrict__ wv,
                             u16* __restrict__ wqb, u16* __restrict__ wkb, u16* __restrict__ wvb) {
    int i = blockIdx.x * blockDim.x + threadIdx.x;   // grid covers C_*C_
    wqb[i] = f2bf(wq[i]);
    wkb[i] = f2bf(wk[i]);
    wvb[i] = f2bf(wv[i]);
}

// ---------------- kernel 2: pose [B,C,N] f32 -> poseT [B,N,C] bf16 ----------------
__global__ void transpose_kernel(const float* __restrict__ pose, u16* __restrict__ poseT) {
    __shared__ float tile[64][65];
    int bid = blockIdx.x;              // B * 4 * 64 = 1024
    int b = bid >> 8;
    int rem = bid & 255;
    int ct = rem >> 6;                 // c-tile 0..3
    int nt = rem & 63;                 // n-tile 0..63
    int c0 = ct * 64, n0 = nt * 64;
    int tid = threadIdx.x;
    int lo = tid & 63, hi = tid >> 6;  // hi 0..3
#pragma unroll
    for (int r = 0; r < 16; ++r) {
        int cc = r * 4 + hi;
        tile[cc][lo] = pose[(size_t)(b * C_ + c0 + cc) * N_ + n0 + lo];
    }
    __syncthreads();
#pragma unroll
    for (int r = 0; r < 16; ++r) {
        int nn = r * 4 + hi;
        poseT[(size_t)(b * N_ + n0 + nn) * C_ + c0 + lo] = f2bf(tile[lo][nn]);
    }
}

// ---------------- kernel 3: projections ----------------
// Qm,Km: [B][N][C] bf16 ; Vm: [B][C][N] bf16
__global__ __launch_bounds__(256) void proj_kernel(
    const u16* __restrict__ poseT,
    const u16* __restrict__ wqb, const float* __restrict__ bq,
    const u16* __restrict__ wkb, const float* __restrict__ bk,
    const u16* __restrict__ wvb, const float* __restrict__ bv,
    u16* __restrict__ Qm, u16* __restrict__ Km, u16* __restrict__ Vm)
{
    int bid = blockIdx.x;              // B * N/64 = 256
    int b = bid >> 6;
    int n0 = (bid & 63) * 64;
    int lane = threadIdx.x & 63;
    int wav = threadIdx.x >> 6;        // 0..3
    int l15 = lane & 15, lg = lane >> 4;

    // ---- Q and K: out[n][d], wave owns 16 n-rows ----
    int nrow = n0 + wav * 16;
    const u16* arow = poseT + (size_t)(b * N_ + nrow + l15) * C_;
    bf16x8 afr[8];
#pragma unroll
    for (int kc = 0; kc < 8; ++kc)
        afr[kc] = *(const bf16x8*)(arow + kc * 32 + lg * 8);

    for (int qk = 0; qk < 2; ++qk) {
        const u16* wb = qk ? wkb : wqb;
        const float* bias = qk ? bk : bq;
        u16* outm = qk ? Km : Qm;
#pragma unroll
        for (int ct = 0; ct < 16; ++ct) {
            f32x4 acc = {0.f, 0.f, 0.f, 0.f};
            const u16* brow = wb + (size_t)(ct * 16 + l15) * C_;
#pragma unroll
            for (int kc = 0; kc < 8; ++kc) {
                bf16x8 bfr = *(const bf16x8*)(brow + kc * 32 + lg * 8);
                acc = mfma16(afr[kc], bfr, acc);
            }
            float bias_v = bias[ct * 16 + l15];
#pragma unroll
            for (int reg = 0; reg < 4; ++reg) {
                int nr = nrow + lg * 4 + reg;
                outm[(size_t)(b * N_ + nr) * C_ + ct * 16 + l15] = f2bf(acc[reg] + bias_v);
            }
        }
    }

    // ---- V: out[d][n], wave owns 64 d-rows ----
    int d0w = wav * 64;
#pragma unroll
    for (int dt = 0; dt < 4; ++dt) {
        const u16* awrow = wvb + (size_t)(d0w + dt * 16 + l15) * C_;
        bf16x8 av[8];
#pragma unroll
        for (int kc = 0; kc < 8; ++kc)
            av[kc] = *(const bf16x8*)(awrow + kc * 32 + lg * 8);
#pragma unroll
        for (int nt = 0; nt < 4; ++nt) {
            f32x4 acc = {0.f, 0.f, 0.f, 0.f};
            const u16* brow = poseT + (size_t)(b * N_ + n0 + nt * 16 + l15) * C_;
#pragma unroll
            for (int kc = 0; kc < 8; ++kc) {
                bf16x8 bfr = *(const bf16x8*)(brow + kc * 32 + lg * 8);
                acc = mfma16(av[kc], bfr, acc);
            }
#pragma unroll
            for (int reg = 0; reg < 4; ++reg) {
                int dd = d0w + dt * 16 + lg * 4 + reg;
                Vm[(size_t)(b * C_ + dd) * N_ + n0 + nt * 16 + l15] = f2bf(acc[reg] + bv[dd]);
            }
        }
    }
}

// ---------------- kernel 4: fused flash attention (in-block 4-way j-split) ----------------
// 1024 threads = 16 waves: wave w -> i-rows (w&3)*16.., j-quarter (w>>2)
__global__ __launch_bounds__(1024) void attn_kernel(
    const u16* __restrict__ Qm, const u16* __restrict__ Km, const u16* __restrict__ Vm,
    const float* __restrict__ pose, const float* __restrict__ gamma_p,
    float* __restrict__ out)
{
    // Qlds u16[64][264] (33792 B) aliases buf0/buf1 f32[64][66] x2 (33792 B)
    __shared__ __align__(16) char smem_u[64 * 528];
    __shared__ float m_s[4][64], l_s[4][64];

    u16* Qlds = (u16*)smem_u;
    float* buf0 = (float*)smem_u;                    // [64][66]
    float* buf1 = (float*)(smem_u + 64 * 66 * 4);    // [64][66]

    int d = blockIdx.x;                 // 256
    int xcd = d & 7;                    // XCD pinning: batch b -> 2 XCDs
    int b = xcd >> 1;
    int i0 = ((xcd & 1) * 32 + (d >> 3)) * 64;

    int tid = threadIdx.x;
    int lane = tid & 63;
    int w = tid >> 6;                   // 0..15
    int isub = w & 3;
    int par = w >> 2;                   // j-quarter 0..3
    int l15 = lane & 15, lg = lane >> 4;

    // ---- stage Q tile (64 rows x 256) into LDS, stride 264 (bank-friendly) ----
    {
        const u16* qbase = Qm + (size_t)(b * N_ + i0) * C_;
        int c0 = tid * 2;
#pragma unroll
        for (int cc = 0; cc < 2; ++cc) {
            int c = c0 + cc;
            int row = c >> 5, col = c & 31;
            bf16x8 v = *(const bf16x8*)(qbase + (size_t)row * C_ + col * 8);
            *(bf16x8*)(Qlds + row * 264 + col * 8) = v;
        }
    }
    __syncthreads();

    f32x4 Ot[16];
#pragma unroll
    for (int ct = 0; ct < 16; ++ct) Ot[ct] = (f32x4){0.f, 0.f, 0.f, 0.f};
    float m_r = -1e30f, l_r = 0.f;

    const u16* Kb = Km + (size_t)b * N_ * C_;
    const u16* Vb = Vm + (size_t)b * C_ * N_;
    const u16* qrow_lds = Qlds + (isub * 16 + l15) * 264 + lg * 8;

    for (int jt = 0; jt < 16; ++jt) {
        int j0 = par * 1024 + jt * 64;
        const u16* kptr = Kb + (size_t)(j0 + l15) * C_ + lg * 8;
        const u16* vptr = Vb + (size_t)l15 * N_ + j0 + lg * 8;

        // ---- QK^T swapped: sT[t] row=j (t*16+lg*4+reg), col=i (l15) ----
        f32x4 sT[4];
#pragma unroll
        for (int t = 0; t < 4; ++t) sT[t] = (f32x4){0.f, 0.f, 0.f, 0.f};
        bf16x8 kf2[2][4], qf2[2];
        qf2[0] = *(const bf16x8*)(qrow_lds);
#pragma unroll
        for (int t = 0; t < 4; ++t)
            kf2[0][t] = *(const bf16x8*)(kptr + (size_t)t * 16 * C_);
#pragma unroll
        for (int kc = 0; kc < 8; ++kc) {
            int cur = kc & 1, nx = cur ^ 1;
            if (kc < 7) {
                qf2[nx] = *(const bf16x8*)(qrow_lds + (kc + 1) * 32);
#pragma unroll
                for (int t = 0; t < 4; ++t)
                    kf2[nx][t] = *(const bf16x8*)(kptr + (size_t)t * 16 * C_ + (kc + 1) * 32);
            }
#pragma unroll
            for (int t = 0; t < 4; ++t)
                sT[t] = mfma16(kf2[cur][t], qf2[cur], sT[t]);
        }

        // prefetch V for ct=0 (hide under softmax)
        bf16x8 vf2[2][2];
#pragma unroll
        for (int ks = 0; ks < 2; ++ks)
            vf2[0][ks] = *(const bf16x8*)(vptr + ks * 32);

        // ---- softmax: lane holds 16 j-scores for q-row i = isub*16+l15 ----
        float pm = sT[0][0];
#pragma unroll
        for (int t = 0; t < 4; ++t)
#pragma unroll
            for (int r = 0; r < 4; ++r) pm = fmaxf(pm, sT[t][r]);
        pm = fmaxf(pm, __shfl_xor(pm, 16));
        pm = fmaxf(pm, __shfl_xor(pm, 32));
        float mn = fmaxf(m_r, pm);
        float sc = __expf(m_r - mn);
        m_r = mn;
        float p[4][4];
        float rs = 0.f;
#pragma unroll
        for (int t = 0; t < 4; ++t)
#pragma unroll
            for (int r = 0; r < 4; ++r) {
                p[t][r] = __expf(sT[t][r] - mn);
                rs += p[t][r];
            }
        rs += __shfl_xor(rs, 16);
        rs += __shfl_xor(rs, 32);
        l_r = l_r * sc + rs;

        // pack p -> bf16 pairs: wpk[t][h] = {p[t][2h], p[t][2h+1]}
        unsigned wpk[4][2];
#pragma unroll
        for (int t = 0; t < 4; ++t)
#pragma unroll
            for (int h = 0; h < 2; ++h)
                wpk[t][h] = (unsigned)f2bf(p[t][2 * h]) | ((unsigned)f2bf(p[t][2 * h + 1]) << 16);

        // build PV A-frags in-register: af[ks] word wi = P[i=l15][j=ks*32+lg*8+2wi..+1]
        union { bf16x8 v; unsigned uw[4]; } afu[2];
#pragma unroll
        for (int ks = 0; ks < 2; ++ks)
#pragma unroll
            for (int wi = 0; wi < 4; ++wi) {
                int go = ((lg & 1) << 1) + (wi >> 1);
                int addr = (l15 + 16 * go) << 2;
                int b0 = __builtin_amdgcn_ds_bpermute(addr, (int)wpk[2 * ks][wi & 1]);
                int b1 = __builtin_amdgcn_ds_bpermute(addr, (int)wpk[2 * ks + 1][wi & 1]);
                afu[ks].uw[wi] = (unsigned)((lg & 2) ? b1 : b0);
            }

        // broadcast rescale factor to O-row layout (i = lg*4+reg)
        float scb[4];
#pragma unroll
        for (int r = 0; r < 4; ++r)
            scb[r] = __uint_as_float(
                (unsigned)__builtin_amdgcn_ds_bpermute((lg * 4 + r) << 2, (int)__float_as_uint(sc)));
#pragma unroll
        for (int ct = 0; ct < 16; ++ct)
#pragma unroll
            for (int r = 0; r < 4; ++r) Ot[ct][r] *= scb[r];

        // ---- PV: Ot[ct] (rows=i, cols=d=ct*16+l15), depth-2 V pipeline ----
#pragma unroll
        for (int ct = 0; ct < 16; ++ct) {
            int cur = ct & 1, nx = cur ^ 1;
            if (ct < 15) {
#pragma unroll
                for (int ks = 0; ks < 2; ++ks)
                    vf2[nx][ks] = *(const bf16x8*)(vptr + (size_t)(ct + 1) * 16 * N_ + ks * 32);
            }
#pragma unroll
            for (int ks = 0; ks < 2; ++ks)
                Ot[ct] = mfma16(afu[ks].v, vf2[cur][ks], Ot[ct]);
        }
    }

    // ---- merge 4 j-partials in LDS, normalize, +residual, store ----
    if (lg == 0) {
        m_s[par][isub * 16 + l15] = m_r;
        l_s[par][isub * 16 + l15] = l_r;
    }
    __syncthreads();

    float scp[4], invL[4];
#pragma unroll
    for (int r = 0; r < 4; ++r) {
        int ig = isub * 16 + lg * 4 + r;
        float m0 = m_s[0][ig], m1 = m_s[1][ig], m2 = m_s[2][ig], m3 = m_s[3][ig];
        float M = fmaxf(fmaxf(m0, m1), fmaxf(m2, m3));
        float e0 = __expf(m0 - M), e1 = __expf(m1 - M), e2 = __expf(m2 - M), e3 = __expf(m3 - M);
        float L = l_s[0][ig] * e0 + l_s[1][ig] * e1 + l_s[2][ig] * e2 + l_s[3][ig] * e3;
        invL[r] = 1.0f / L;
        scp[r] = (par == 0) ? e0 : (par == 1) ? e1 : (par == 2) ? e2 : e3;
    }

    float g = gamma_p[0];
    int r_base = isub * 16 + lg * 4;
#pragma unroll
    for (int cc = 0; cc < 4; ++cc) {
        __syncthreads();
        // R1: par1 -> buf0, par3 -> buf1 (scaled partials)
        if (par & 1) {
            float* bufp = (par == 1) ? buf0 : buf1;
#pragma unroll
            for (int u = 0; u < 4; ++u)
#pragma unroll
                for (int r = 0; r < 4; ++r)
                    bufp[(r_base + r) * 66 + u * 16 + l15] = Ot[cc * 4 + u][r] * scp[r];
        }
        __syncthreads();
        // R2: par0 adds into buf0, par2 adds into buf1
        if (!(par & 1)) {
            float* bufp = (par == 0) ? buf0 : buf1;
#pragma unroll
            for (int u = 0; u < 4; ++u)
#pragma unroll
                for (int r = 0; r < 4; ++r) {
                    int idx = (r_base + r) * 66 + u * 16 + l15;
                    bufp[idx] += Ot[cc * 4 + u][r] * scp[r];
                }
        }
        __syncthreads();
        // R3: merged = (buf0+buf1)*invL ; wave covers own rows x d-col group par*16+l15
#pragma unroll
        for (int r = 0; r < 4; ++r) {
            int idx = (r_base + r) * 66 + par * 16 + l15;
            buf0[idx] = (buf0[idx] + buf1[idx]) * invL[r];
        }
        __syncthreads();
        // store: wave w -> c-rows w*4..w*4+3, coalesced over i (=lane)
#pragma unroll
        for (int r = 0; r < 4; ++r) {
            int cic = w * 4 + r;
            size_t addr = (size_t)(b * C_ + cc * 64 + cic) * N_ + i0 + lane;
            out[addr] = pose[addr] + g * buf0[lane * 66 + cic];
        }
    }
}

extern "C" void kernel_launch(void* const* d_in, const int* in_sizes, int n_in,
                              void* d_out, int out_size, void* d_ws, size_t ws_size,
                              hipStream_t stream) {
    (void)in_sizes; (void)n_in; (void)out_size; (void)ws_size;
    const float* pose = (const float*)d_in[0];
    const float* wq = (const float*)d_in[1];
    const float* bq = (const float*)d_in[2];
    const float* wk = (const float*)d_in[3];
    const float* bk = (const float*)d_in[4];
    const float* wv = (const float*)d_in[5];
    const float* bv = (const float*)d_in[6];
    const float* gamma = (const float*)d_in[7];
    float* out = (float*)d_out;

    char* ws = (char*)d_ws;
    u16* wqb   = (u16*)(ws + 0);
    u16* wkb   = (u16*)(ws + (128 << 10));
    u16* wvb   = (u16*)(ws + (256 << 10));
    u16* poseT = (u16*)(ws + (1 << 20));     // 8 MB
    u16* Qm    = (u16*)(ws + (9 << 20));     // 8 MB
    u16* Km    = (u16*)(ws + (17 << 20));    // 8 MB
    u16* Vm    = (u16*)(ws + (25 << 20));    // 8 MB -> 33 MB total

    hipLaunchKernelGGL(wconv_kernel, dim3(256), dim3(256), 0, stream, wq, wk, wv, wqb, wkb, wvb);
    hipLaunchKernelGGL(transpose_kernel, dim3(1024), dim3(256), 0, stream, pose, poseT);
    hipLaunchKernelGGL(proj_kernel, dim3(256), dim3(256), 0, stream,
                       poseT, wqb, bq, wkb, bk, wvb, bv, Qm, Km, Vm);
    hipLaunchKernelGGL(attn_kernel, dim3(256), dim3(1024), 0, stream,
                       Qm, Km, Vm, pose, gamma, out);
}